// Round 3
// baseline (592.271 us; speedup 1.0000x reference)
//
#include <hip/hip_runtime.h>
#include <math.h>

// SparseDiffAttn: B=1,H=12,N=2048,D=128, BM=64, top-k=192, static window [c-153,c+153),
// random keys via modern-JAX randint under jax_threefry_partitionable=True:
//   k1 = tf((0,1),(0,0)), k2 = tf((0,1),(0,1))        [fold-like split]
//   bits(k,i) = b1^b2 with (b1,b2) = tf(k,(0,i))      [partitionable random_bits]
//   offset = ((hi%100)*96 + lo%100) % 100; rnd <=> offset==0
// PRECISION: selection robust to ~1e-6 rel (fp32==fp64 masks) but NOT fp16-E (R10, 5e-4).
// Split-fp16 MFMA QK (hi·hi + hi·lo + lo·hi) err ~1e-7 rel — inside the certified band.
// RULES LEARNED: (a) no register prefetch in k3 — R8/R13; (c) k3 XCD swizzle: FETCH 157->28MB.
// R19/R20 ATTRIBUTION: each MFMA-QK pass ~168us, INVARIANT to conversion VALU (R20: k0
// hoist was neutral), register pressure, and E-store removal (R18). Arithmetic floor is
// ~5us MFMA + ~25us coalesced traffic => the invariant 170us must be fragment traffic
// served BELOW L2 at ~1.1 TB/s ("E-stream floor" = L3 service rate, misattributed before).
// THIS ROUND: XCD swizzle on k1/k2r (per-XCD contiguous chunk -> ~3MB working set fits
// 4MB L2, same fix that took k3 157->28MB) + halved column tile (tc=4, 6144 blocks,
// launch_bounds(256,4) -> ~4 waves/SIMD). Per-column math bit-identical; l partial
// grouping 16->32 (order preserved) ~1e-7 shift, inside band. k0/k2b/k3 untouched.
constexpr int Hh   = 12;
constexpr int Nn   = 2048;
constexpr int Dd   = 128;
constexpr int BMq  = 64;
constexpr int QGg  = 32;            // Nn/BMq
constexpr int KSEL = 192;           // 64 * round(0.1*2048/64)
constexpr int CK   = 32;            // key chunk (k3)
constexpr float SCALE = 0.08838834764831845f;  // 1/sqrt(128)

typedef _Float16 v8h __attribute__((ext_vector_type(8)));   // MFMA A/B frag (4 VGPRs)
typedef _Float16 v4h __attribute__((ext_vector_type(4)));
typedef float    v4f __attribute__((ext_vector_type(4)));   // MFMA C/D frag

// persistent scratch (fully rewritten every launch before any read)
__device__ __attribute__((aligned(16))) _Float16 g_qh[(size_t)Hh*Nn*Dd];  // Q*SCALE hi
__device__ __attribute__((aligned(16))) _Float16 g_ql[(size_t)Hh*Nn*Dd];  // Q*SCALE lo
__device__ __attribute__((aligned(16))) _Float16 g_kh[(size_t)Hh*Nn*Dd];  // K hi
__device__ __attribute__((aligned(16))) _Float16 g_kl[(size_t)Hh*Nn*Dd];  // K lo
__device__ float          g_lp[(size_t)Hh*Nn*32];           // per-jb2 partial row sums
__device__ float          g_bs[(size_t)Hh*QGg*Nn];          // colsum scores (3 MB)
__device__ unsigned short g_sel[Hh*QGg*Nn];
__device__ int            g_cnt[Hh*QGg];

__device__ __forceinline__ unsigned int rotl32(unsigned int x, int n){
  return (x << n) | (x >> (32 - n));
}

// threefry2x32, 20 rounds, arbitrary key
__device__ __forceinline__ void tf2x32(unsigned int k0, unsigned int k1,
                                       unsigned int x0, unsigned int x1,
                                       unsigned int &o0, unsigned int &o1){
  const unsigned int ks2 = 0x1BD11BDAu ^ k0 ^ k1;
  x0 += k0; x1 += k1;
  x0 += x1; x1 = rotl32(x1,13); x1 ^= x0;
  x0 += x1; x1 = rotl32(x1,15); x1 ^= x0;
  x0 += x1; x1 = rotl32(x1,26); x1 ^= x0;
  x0 += x1; x1 = rotl32(x1, 6); x1 ^= x0;
  x0 += k1; x1 += ks2 + 1u;
  x0 += x1; x1 = rotl32(x1,17); x1 ^= x0;
  x0 += x1; x1 = rotl32(x1,29); x1 ^= x0;
  x0 += x1; x1 = rotl32(x1,16); x1 ^= x0;
  x0 += x1; x1 = rotl32(x1,24); x1 ^= x0;
  x0 += ks2; x1 += k0 + 2u;
  x0 += x1; x1 = rotl32(x1,13); x1 ^= x0;
  x0 += x1; x1 = rotl32(x1,15); x1 ^= x0;
  x0 += x1; x1 = rotl32(x1,26); x1 ^= x0;
  x0 += x1; x1 = rotl32(x1, 6); x1 ^= x0;
  x0 += k0; x1 += k1 + 3u;
  x0 += x1; x1 = rotl32(x1,17); x1 ^= x0;
  x0 += x1; x1 = rotl32(x1,29); x1 ^= x0;
  x0 += x1; x1 = rotl32(x1,16); x1 ^= x0;
  x0 += x1; x1 = rotl32(x1,24); x1 ^= x0;
  x0 += k1; x1 += ks2 + 4u;
  x0 += x1; x1 = rotl32(x1,13); x1 ^= x0;
  x0 += x1; x1 = rotl32(x1,15); x1 ^= x0;
  x0 += x1; x1 = rotl32(x1,26); x1 ^= x0;
  x0 += x1; x1 = rotl32(x1, 6); x1 ^= x0;
  x0 += ks2; x1 += k0 + 5u;
  o0 = x0; o1 = x1;
}

// partitionable-threefry randint(key(1), ..., 0, 100) == 0 for flat element idx
__device__ __forceinline__ bool jax_rand01(unsigned int idx,
                                           unsigned int k1a, unsigned int k1b,
                                           unsigned int k2a, unsigned int k2b){
  unsigned int h0, h1, l0, l1;
  tf2x32(k1a, k1b, 0u, idx, h0, h1);
  tf2x32(k2a, k2b, 0u, idx, l0, l1);
  unsigned int h = h0 ^ h1;
  unsigned int l = l0 ^ l1;
  unsigned int off = ((h % 100u) * 96u + (l % 100u)) % 100u;
  return off == 0u;
}

// ---------------- Kernel 0: one-shot split-fp16 conversion of Q (scaled) and K ----------------
__global__ __launch_bounds__(256) void k0_cvt(const float* __restrict__ Q,
                                              const float* __restrict__ K){
  const size_t i = (size_t)blockIdx.x*256 + threadIdx.x;   // float4 index
  float4 q = ((const float4*)Q)[i];
  float qs[4] = {q.x*SCALE, q.y*SCALE, q.z*SCALE, q.w*SCALE};
  v4h qh, ql;
  #pragma unroll
  for (int j = 0; j < 4; ++j){
    _Float16 hi = (_Float16)qs[j];
    qh[j] = hi;
    ql[j] = (_Float16)(qs[j] - (float)hi);
  }
  *(v4h*)&g_qh[i*4] = qh;
  *(v4h*)&g_ql[i*4] = ql;
  float4 k = ((const float4*)K)[i];
  float ks[4] = {k.x, k.y, k.z, k.w};
  v4h kh, kl;
  #pragma unroll
  for (int j = 0; j < 4; ++j){
    _Float16 hi = (_Float16)ks[j];
    kh[j] = hi;
    kl[j] = (_Float16)(ks[j] - (float)hi);
  }
  *(v4h*)&g_kh[i*4] = kh;
  *(v4h*)&g_kl[i*4] = kl;
}

// ---------------- Kernel 1: MFMA split-fp16 QK -> exp -> row-sum partials ----------------
// 128x64 tile per block (tc=4), 4 waves x (2 tile-rows x 4 tile-cols) of 16x16x32_f16.
// XCD-swizzled block order: each XCD owns a contiguous chunk of (h,gp,jb2) space.
// A layout: lane holds A[m=lane&15][k=quad*8+j]; B: B[n=lane&15][k=quad*8+j];
// D layout (HW-verified m89/m91): col=lane&15, row=quad*4+reg. No LDS, no barriers.
__global__ __launch_bounds__(256, 4) void k1_rowsum(){
  const int bid0 = blockIdx.x;
  const int w = (bid0 & 7)*768 + (bid0 >> 3);     // 6144 blocks, xcd-contiguous
  const int jb2 = w & 31, gp = (w >> 5) & 15, h = w >> 9;
  const int t = threadIdx.x;
  const int wv = t >> 6, ln = t & 63;
  const int nidx = ln & 15, quad = ln >> 4;
  const int R0 = gp*128, J0 = jb2*64;

  v4f acc[2][4];
  #pragma unroll
  for (int tr = 0; tr < 2; ++tr)
    #pragma unroll
    for (int tc = 0; tc < 4; ++tc)
      acc[tr][tc] = (v4f){0.f, 0.f, 0.f, 0.f};

  for (int kc = 0; kc < 4; ++kc){
    const int dofs = kc*32 + quad*8;
    v8h ahi[2], alo[2];
    #pragma unroll
    for (int tr = 0; tr < 2; ++tr){
      const size_t off = ((size_t)h*Nn + R0 + (wv*2+tr)*16 + nidx)*Dd + dofs;
      ahi[tr] = *(const v8h*)&g_qh[off];
      alo[tr] = *(const v8h*)&g_ql[off];
    }
    v8h bhi[4], blo[4];
    #pragma unroll
    for (int tc = 0; tc < 4; ++tc){
      const size_t off = ((size_t)h*Nn + J0 + tc*16 + nidx)*Dd + dofs;
      bhi[tc] = *(const v8h*)&g_kh[off];
      blo[tc] = *(const v8h*)&g_kl[off];
    }
    #pragma unroll
    for (int tr = 0; tr < 2; ++tr)
      #pragma unroll
      for (int tc = 0; tc < 4; ++tc){
        acc[tr][tc] = __builtin_amdgcn_mfma_f32_16x16x32_f16(ahi[tr], bhi[tc], acc[tr][tc], 0, 0, 0);
        acc[tr][tc] = __builtin_amdgcn_mfma_f32_16x16x32_f16(ahi[tr], blo[tc], acc[tr][tc], 0, 0, 0);
        acc[tr][tc] = __builtin_amdgcn_mfma_f32_16x16x32_f16(alo[tr], bhi[tc], acc[tr][tc], 0, 0, 0);
      }
  }

  // epilogue: exp, shfl-reduced row sums -> g_lp (column-ascending order preserved)
  #pragma unroll
  for (int tr = 0; tr < 2; ++tr){
    float rs[4] = {0.f, 0.f, 0.f, 0.f};
    #pragma unroll
    for (int tc = 0; tc < 4; ++tc){
      #pragma unroll
      for (int r = 0; r < 4; ++r){
        rs[r] += __expf(acc[tr][tc][r]);
      }
    }
    #pragma unroll
    for (int r = 0; r < 4; ++r){
      float v = rs[r];
      v += __shfl_xor(v, 1);
      v += __shfl_xor(v, 2);
      v += __shfl_xor(v, 4);
      v += __shfl_xor(v, 8);
      rs[r] = v;
    }
    if (nidx == 0){
      #pragma unroll
      for (int r = 0; r < 4; ++r){
        const int row = (wv*2+tr)*16 + quad*4 + r;
        g_lp[((size_t)h*Nn + R0 + row)*32 + jb2] = rs[r];
      }
    }
  }
}

// ---------------- Kernel 2r: MFMA QK recompute -> weighted colsum -> g_bs ----------------
// Same tile body as k1. Tile (h,gp,jb2) owns bs[g=2gp..2gp+1][cols jb2*64..+63]:
// no cross-tile reduction needed. il reduced from g_lp with x=0..31 ascending.
// Colsum: per-lane r-sum -> quad butterfly (xor16,xor32) -> tr -> wave pair.
__global__ __launch_bounds__(256, 4) void k2r_colsum(){
  const int bid0 = blockIdx.x;
  const int w = (bid0 & 7)*768 + (bid0 >> 3);     // 6144 blocks, xcd-contiguous
  const int jb2 = w & 31, gp = (w >> 5) & 15, h = w >> 9;
  const int t = threadIdx.x;
  const int wv = t >> 6, ln = t & 63;
  const int nidx = ln & 15, quad = ln >> 4;
  const int R0 = gp*128, J0 = jb2*64;

  __shared__ float il_s[128];
  __shared__ float part[4][64];
  if (t < 128){
    const float* lp = &g_lp[((size_t)h*Nn + R0 + t)*32];
    float s = 0.f;
    #pragma unroll
    for (int x = 0; x < 32; ++x) s += lp[x];
    il_s[t] = 1.0f / s;
  }
  __syncthreads();

  v4f acc[2][4];
  #pragma unroll
  for (int tr = 0; tr < 2; ++tr)
    #pragma unroll
    for (int tc = 0; tc < 4; ++tc)
      acc[tr][tc] = (v4f){0.f, 0.f, 0.f, 0.f};

  for (int kc = 0; kc < 4; ++kc){
    const int dofs = kc*32 + quad*8;
    v8h ahi[2], alo[2];
    #pragma unroll
    for (int tr = 0; tr < 2; ++tr){
      const size_t off = ((size_t)h*Nn + R0 + (wv*2+tr)*16 + nidx)*Dd + dofs;
      ahi[tr] = *(const v8h*)&g_qh[off];
      alo[tr] = *(const v8h*)&g_ql[off];
    }
    v8h bhi[4], blo[4];
    #pragma unroll
    for (int tc = 0; tc < 4; ++tc){
      const size_t off = ((size_t)h*Nn + J0 + tc*16 + nidx)*Dd + dofs;
      bhi[tc] = *(const v8h*)&g_kh[off];
      blo[tc] = *(const v8h*)&g_kl[off];
    }
    #pragma unroll
    for (int tr = 0; tr < 2; ++tr)
      #pragma unroll
      for (int tc = 0; tc < 4; ++tc){
        acc[tr][tc] = __builtin_amdgcn_mfma_f32_16x16x32_f16(ahi[tr], bhi[tc], acc[tr][tc], 0, 0, 0);
        acc[tr][tc] = __builtin_amdgcn_mfma_f32_16x16x32_f16(ahi[tr], blo[tc], acc[tr][tc], 0, 0, 0);
        acc[tr][tc] = __builtin_amdgcn_mfma_f32_16x16x32_f16(alo[tr], bhi[tc], acc[tr][tc], 0, 0, 0);
      }
  }

  // weighted colsum epilogue. Wave wv covers tile rows [wv*32, wv*32+32).
  float csg[4];
  #pragma unroll
  for (int tc = 0; tc < 4; ++tc) csg[tc] = 0.f;
  #pragma unroll
  for (int tr = 0; tr < 2; ++tr){
    #pragma unroll
    for (int tc = 0; tc < 4; ++tc){
      float cs = 0.f;
      #pragma unroll
      for (int r = 0; r < 4; ++r){
        const int row = (wv*2+tr)*16 + quad*4 + r;
        cs += __expf(acc[tr][tc][r]) * il_s[row];
      }
      cs += __shfl_xor(cs, 16);   // sum across the 4 quads (16 rows of this tile-row)
      cs += __shfl_xor(cs, 32);
      csg[tc] += cs;
    }
  }
  if (ln < 16){                    // quad 0 publishes this wave's 64 col-partials
    #pragma unroll
    for (int tc = 0; tc < 4; ++tc) part[wv][tc*16 + nidx] = csg[tc];
  }
  __syncthreads();
  // waves 0+1 = rows 0..63 = group 2gp; waves 2+3 = group 2gp+1
  if (t < 128){
    const int col = t & 63, grp = t >> 6;
    g_bs[((size_t)h*QGg + gp*2 + grp)*Nn + jb2*64 + col] =
        part[grp*2][col] + part[grp*2 + 1][col];
  }
}

// ---------------- Kernel 2b: top-k + random + static window -> compacted key list ----------------
__global__ __launch_bounds__(256) void k2b_mask(){
  const int bid = blockIdx.x, g = bid % QGg, t = threadIdx.x;
  __shared__ float bsv[Nn];
  __shared__ int red[33];
  __shared__ int csel;
  const float* src = g_bs + (size_t)bid*Nn;
  float mine[8];
  {
    float4 a = *(const float4*)&src[t*4];
    float4 b = *(const float4*)&src[1024 + t*4];
    *(float4*)&bsv[t*4] = a;
    *(float4*)&bsv[1024 + t*4] = b;
    mine[0]=a.x; mine[1]=a.y; mine[2]=a.z; mine[3]=a.w;
    mine[4]=b.x; mine[5]=b.y; mine[6]=b.z; mine[7]=b.w;
  }
  if (t < 33) red[t] = 0;
  if (t == 0) csel = 0;
  __syncthreads();

  unsigned int k1a, k1b, k2a, k2b;
  tf2x32(0u, 1u, 0u, 0u, k1a, k1b);
  tf2x32(0u, 1u, 0u, 1u, k2a, k2b);

  // 192nd-largest via bitwise binary search (positive -> uint order)
  unsigned int prefix = 0u;
  for (int bit = 31; bit >= 0; --bit){
    unsigned int cand = prefix | (1u << bit);
    int c = 0;
    #pragma unroll
    for (int u = 0; u < 8; ++u)
      c += (__float_as_uint(mine[u]) >= cand) ? 1 : 0;
    #pragma unroll
    for (int off = 32; off > 0; off >>= 1) c += __shfl_down(c, off);
    if ((t & 63) == 0) atomicAdd(&red[bit], c);
    __syncthreads();
    if (red[bit] >= KSEL) prefix = cand;
  }
  {
    int cg = 0;
    #pragma unroll
    for (int u = 0; u < 8; ++u)
      cg += (__float_as_uint(mine[u]) > prefix) ? 1 : 0;
    #pragma unroll
    for (int off = 32; off > 0; off >>= 1) cg += __shfl_down(cg, off);
    if ((t & 63) == 0) atomicAdd(&red[32], cg);
  }
  __syncthreads();
  const int need = KSEL - red[32];   // ties taken lowest-index-first (jax top_k)

  const int lo = g*BMq + BMq/2 - 153;   // ws=int(0.15*2048)=307, ws//2=153
  const int hi = g*BMq + BMq/2 + 153;
  const int ssum = ((hi < Nn) ? hi : Nn) - ((lo > 0) ? lo : 0);
  const bool vqg = (ssum + KSEL) < Nn;  // always true at this config

  #pragma unroll
  for (int u = 0; u < 8; ++u){
    int j = (u < 4) ? (t*4 + u) : (1024 + t*4 + u - 4);
    unsigned int bu = __float_as_uint(mine[u]);
    bool topk = bu > prefix;
    if (!topk && bu == prefix){
      int tr = 0;
      for (int jj = 0; jj < j; ++jj)
        tr += (__float_as_uint(bsv[jj]) == prefix) ? 1 : 0;
      topk = (tr < need);
    }
    bool rnd = jax_rand01((unsigned)(bid*Nn + j), k1a, k1b, k2a, k2b);
    bool st  = (j >= lo) && (j < hi);
    bool selb = st || ((rnd || topk) && vqg);
    if (selb){
      int slot = atomicAdd(&csel, 1);
      g_sel[(size_t)bid*Nn + slot] = (unsigned short)j;
    }
  }
  __syncthreads();
  if (t == 0) g_cnt[bid] = csel;
}

// ---------------- Kernel 3: one-pass attention, XCD-swizzled, NO prefetch ----------------
__global__ __launch_bounds__(256) void k3_attn(const float* __restrict__ Q,
                                               const float* __restrict__ K,
                                               const float* __restrict__ V,
                                               const float* __restrict__ OC,
                                               float* __restrict__ out){
  const int bid0 = blockIdx.x;
  const int w    = (bid0 & 7)*96 + (bid0 >> 3);   // xcd-grouped work index
  const int half = w & 1;
  const int gg   = w >> 1;             // h*QGg + g
  const int h = gg / QGg, g = gg % QGg;
  const int t = threadIdx.x;
  __shared__ float q_s[32][Dd+4];
  __shared__ float kv_s[CK][Dd+4];
  __shared__ float s_s[32][CK+1];
  __shared__ float l_s[32];
  const int c = g_cnt[gg];
  const unsigned short* sel = g_sel + (size_t)gg*Nn;

  const float* qb = Q + ((size_t)h*Nn + (size_t)g*BMq + half*32)*Dd;
  #pragma unroll
  for (int it = 0; it < 4; ++it){
    int e = it*256 + t;                 // 1024 float4s = 32 rows x 32 f4
    int row = e >> 5, c4 = e & 31;
    float4 vq = ((const float4*)qb)[e];
    float4 sv; sv.x = vq.x*SCALE; sv.y = vq.y*SCALE; sv.z = vq.z*SCALE; sv.w = vq.w*SCALE;
    *(float4*)&q_s[row][c4*4] = sv;
  }
  if (t < 32) l_s[t] = 0.0f;
  __syncthreads();

  const int rt = t & 15, kcol = (t >> 4)*2;
  const int d0 = (t >> 4)*8;           // PV column group
  float acc2[2][8] = {};

  for (int c0 = 0; c0 < c; c0 += CK){
    const int cc = ((c - c0) < CK) ? (c - c0) : CK;
    // gather K chunk
    #pragma unroll
    for (int it = 0; it < 4; ++it){
      int e = it*256 + t, row = e >> 5, c4 = e & 31;
      int j = (row < cc) ? (int)sel[c0 + row] : 0;
      *(float4*)&kv_s[row][c4*4] = ((const float4*)(K + ((size_t)h*Nn + j)*Dd))[c4];
    }
    __syncthreads();
    float a00=0.f, a01=0.f, a10=0.f, a11=0.f;
    #pragma unroll 8
    for (int d = 0; d < Dd; d += 4){
      float4 k0 = *(const float4*)&kv_s[kcol][d];
      float4 k1 = *(const float4*)&kv_s[kcol+1][d];
      float4 q0 = *(const float4*)&q_s[rt][d];
      float4 q1 = *(const float4*)&q_s[rt+16][d];
      a00 += q0.x*k0.x + q0.y*k0.y + q0.z*k0.z + q0.w*k0.w;
      a01 += q0.x*k1.x + q0.y*k1.y + q0.z*k1.z + q0.w*k1.w;
      a10 += q1.x*k0.x + q1.y*k0.y + q1.z*k0.z + q1.w*k0.w;
      a11 += q1.x*k1.x + q1.y*k1.y + q1.z*k1.z + q1.w*k1.w;
    }
    s_s[rt   ][kcol  ] = (kcol   < cc) ? __expf(a00) : 0.f;
    s_s[rt   ][kcol+1] = (kcol+1 < cc) ? __expf(a01) : 0.f;
    s_s[rt+16][kcol  ] = (kcol   < cc) ? __expf(a10) : 0.f;
    s_s[rt+16][kcol+1] = (kcol+1 < cc) ? __expf(a11) : 0.f;
    __syncthreads();
    if (t < 32){
      float s = 0.f;
      #pragma unroll
      for (int c2 = 0; c2 < CK; ++c2) s += s_s[t][c2];
      l_s[t] += s;
    }
    // gather V chunk (overwrites kv_s; QK readers already past barrier)
    #pragma unroll
    for (int it = 0; it < 4; ++it){
      int e = it*256 + t, row = e >> 5, c4 = e & 31;
      int j = (row < cc) ? (int)sel[c0 + row] : 0;
      *(float4*)&kv_s[row][c4*4] = ((const float4*)(V + ((size_t)h*Nn + j)*Dd))[c4];
    }
    __syncthreads();
    for (int c2 = 0; c2 < cc; ++c2){
      float p0 = s_s[rt][c2], p1 = s_s[rt+16][c2];
      float4 va = *(const float4*)&kv_s[c2][d0];
      float4 vb = *(const float4*)&kv_s[c2][d0+4];
      acc2[0][0] += p0*va.x; acc2[0][1] += p0*va.y;
      acc2[0][2] += p0*va.z; acc2[0][3] += p0*va.w;
      acc2[0][4] += p0*vb.x; acc2[0][5] += p0*vb.y;
      acc2[0][6] += p0*vb.z; acc2[0][7] += p0*vb.w;
      acc2[1][0] += p1*va.x; acc2[1][1] += p1*va.y;
      acc2[1][2] += p1*va.z; acc2[1][3] += p1*va.w;
      acc2[1][4] += p1*vb.x; acc2[1][5] += p1*vb.y;
      acc2[1][6] += p1*vb.z; acc2[1][7] += p1*vb.w;
    }
    __syncthreads();
  }

  if (t < 32) l_s[t] = 1.0f / l_s[t];
  __syncthreads();

  #pragma unroll
  for (int rr = 0; rr < 2; ++rr){
    const int r = rr*16 + rt;
    const float il = l_s[r];
    size_t o = ((size_t)h*Nn + (size_t)g*BMq + half*32 + r)*Dd + d0;
    float4 ca = *(const float4*)(OC + o);
    float4 cb = *(const float4*)(OC + o + 4);
    float4 ra, rb;
    ra.x = acc2[rr][0]*il + ca.x; ra.y = acc2[rr][1]*il + ca.y;
    ra.z = acc2[rr][2]*il + ca.z; ra.w = acc2[rr][3]*il + ca.w;
    rb.x = acc2[rr][4]*il + cb.x; rb.y = acc2[rr][5]*il + cb.y;
    rb.z = acc2[rr][6]*il + cb.z; rb.w = acc2[rr][7]*il + cb.w;
    *(float4*)(out + o)     = ra;
    *(float4*)(out + o + 4) = rb;
  }
}

extern "C" void kernel_launch(void* const* d_in, const int* in_sizes, int n_in,
                              void* d_out, int out_size, void* d_ws, size_t ws_size,
                              hipStream_t stream) {
  (void)in_sizes; (void)n_in; (void)out_size; (void)d_ws; (void)ws_size;
  const float* Q  = (const float*)d_in[0];
  const float* K  = (const float*)d_in[1];
  const float* V  = (const float*)d_in[2];
  const float* OC = (const float*)d_in[3];
  float* out = (float*)d_out;
  hipLaunchKernelGGL(k0_cvt,     dim3(Hh*Nn*Dd/1024), dim3(256), 0, stream, Q, K);
  hipLaunchKernelGGL(k1_rowsum,  dim3(Hh*16*32),      dim3(256), 0, stream);
  hipLaunchKernelGGL(k2r_colsum, dim3(Hh*16*32),      dim3(256), 0, stream);
  hipLaunchKernelGGL(k2b_mask,   dim3(Hh*QGg),        dim3(256), 0, stream);
  hipLaunchKernelGGL(k3_attn,    dim3(Hh*QGg*2),      dim3(256), 0, stream, Q, K, V, OC, out);
}

// Round 6
// 412.737 us; speedup vs baseline: 1.4350x; 1.4350x over previous
//
#include <hip/hip_runtime.h>
#include <math.h>

// SparseDiffAttn: B=1,H=12,N=2048,D=128, BM=64, top-k=192, static window [c-153,c+153),
// random keys via modern-JAX randint under jax_threefry_partitionable=True:
//   k1 = tf((0,1),(0,0)), k2 = tf((0,1),(0,1))        [fold-like split]
//   bits(k,i) = b1^b2 with (b1,b2) = tf(k,(0,i))      [partitionable random_bits]
//   offset = ((hi%100)*96 + lo%100) % 100; rnd <=> offset==0
// PRECISION: selection robust to ~1e-6 rel (fp32==fp64 masks) but NOT fp16-E (R10, 5e-4).
// Split-fp16 MFMA QK (hi·hi + hi·lo + lo·hi) err ~1e-7 rel — inside the certified band.
// RULES: (a) no register prefetch in k3 (R8/R13); (c) k3 XCD swizzle FETCH 157->28MB.
// R19-R21: QK pass ~180us INVARIANT to E-store, conversion VALU, regs, XCD swizzle, tile
// shape. Constant across configs: effective request rate 5.5-6 TB/s with 16 SCATTERED
// 64B lines per fragment load (lane=row => 256B stride). VMEM scatter cost is the wall.
// R22/R23: fragment-ordered relayout test. R4=container-acquire fail; R5=core dump with
// k0's LDS-transpose (only novel code). R23 removes LDS from k0 entirely: each thread
// gathers its own fragment's 8 elements via two float4 loads (32B contiguous, aligned).
// g_qh/ql/kh/kl layout [h][rb16][kc][ln][8]: fragment load = base+ln*16B, one contiguous
// 1KB wave transaction. Values bit-identical (same mul->cvt->sub->cvt). k1/k2r/k2b/k3
// identical to R4.
constexpr int Hh   = 12;
constexpr int Nn   = 2048;
constexpr int Dd   = 128;
constexpr int BMq  = 64;
constexpr int QGg  = 32;            // Nn/BMq
constexpr int KSEL = 192;           // 64 * round(0.1*2048/64)
constexpr int CK   = 32;            // key chunk (k3)
constexpr float SCALE = 0.08838834764831845f;  // 1/sqrt(128)

typedef _Float16 v8h __attribute__((ext_vector_type(8)));   // MFMA A/B frag (4 VGPRs)
typedef float    v4f __attribute__((ext_vector_type(4)));   // MFMA C/D frag

// persistent scratch (fully rewritten every launch before any read)
// fragment-ordered: offset(h,rb,kc,ln,e) = (((h*128+rb)*4+kc)*64+ln)*8+e holds original
// element (row = rb*16 + (ln&15), col = kc*32 + (ln>>4)*8 + e).
__device__ __attribute__((aligned(16))) _Float16 g_qh[(size_t)Hh*Nn*Dd];  // Q*SCALE hi
__device__ __attribute__((aligned(16))) _Float16 g_ql[(size_t)Hh*Nn*Dd];  // Q*SCALE lo
__device__ __attribute__((aligned(16))) _Float16 g_kh[(size_t)Hh*Nn*Dd];  // K hi
__device__ __attribute__((aligned(16))) _Float16 g_kl[(size_t)Hh*Nn*Dd];  // K lo
__device__ float          g_lp[(size_t)Hh*Nn*16];           // per-jb partial row sums
__device__ float          g_bs[(size_t)Hh*QGg*Nn];          // colsum scores (3 MB)
__device__ unsigned short g_sel[Hh*QGg*Nn];
__device__ int            g_cnt[Hh*QGg];

__device__ __forceinline__ unsigned int rotl32(unsigned int x, int n){
  return (x << n) | (x >> (32 - n));
}

// threefry2x32, 20 rounds, arbitrary key
__device__ __forceinline__ void tf2x32(unsigned int k0, unsigned int k1,
                                       unsigned int x0, unsigned int x1,
                                       unsigned int &o0, unsigned int &o1){
  const unsigned int ks2 = 0x1BD11BDAu ^ k0 ^ k1;
  x0 += k0; x1 += k1;
  x0 += x1; x1 = rotl32(x1,13); x1 ^= x0;
  x0 += x1; x1 = rotl32(x1,15); x1 ^= x0;
  x0 += x1; x1 = rotl32(x1,26); x1 ^= x0;
  x0 += x1; x1 = rotl32(x1, 6); x1 ^= x0;
  x0 += k1; x1 += ks2 + 1u;
  x0 += x1; x1 = rotl32(x1,17); x1 ^= x0;
  x0 += x1; x1 = rotl32(x1,29); x1 ^= x0;
  x0 += x1; x1 = rotl32(x1,16); x1 ^= x0;
  x0 += x1; x1 = rotl32(x1,24); x1 ^= x0;
  x0 += ks2; x1 += k0 + 2u;
  x0 += x1; x1 = rotl32(x1,13); x1 ^= x0;
  x0 += x1; x1 = rotl32(x1,15); x1 ^= x0;
  x0 += x1; x1 = rotl32(x1,26); x1 ^= x0;
  x0 += x1; x1 = rotl32(x1, 6); x1 ^= x0;
  x0 += k0; x1 += k1 + 3u;
  x0 += x1; x1 = rotl32(x1,17); x1 ^= x0;
  x0 += x1; x1 = rotl32(x1,29); x1 ^= x0;
  x0 += x1; x1 = rotl32(x1,16); x1 ^= x0;
  x0 += x1; x1 = rotl32(x1,24); x1 ^= x0;
  x0 += k1; x1 += ks2 + 4u;
  x0 += x1; x1 = rotl32(x1,13); x1 ^= x0;
  x0 += x1; x1 = rotl32(x1,15); x1 ^= x0;
  x0 += x1; x1 = rotl32(x1,26); x1 ^= x0;
  x0 += x1; x1 = rotl32(x1, 6); x1 ^= x0;
  x0 += ks2; x1 += k0 + 5u;
  o0 = x0; o1 = x1;
}

// partitionable-threefry randint(key(1), ..., 0, 100) == 0 for flat element idx
__device__ __forceinline__ bool jax_rand01(unsigned int idx,
                                           unsigned int k1a, unsigned int k1b,
                                           unsigned int k2a, unsigned int k2b){
  unsigned int h0, h1, l0, l1;
  tf2x32(k1a, k1b, 0u, idx, h0, h1);
  tf2x32(k2a, k2b, 0u, idx, l0, l1);
  unsigned int h = h0 ^ h1;
  unsigned int l = l0 ^ l1;
  unsigned int off = ((h % 100u) * 96u + (l % 100u)) % 100u;
  return off == 0u;
}

// ---------------- Kernel 0: split-fp16 convert + fragment-order relayout (NO LDS) ----------------
// One block per (h, rb). Thread t owns fragment (kc = t>>6, ln = t&63): reads its 8
// source elements (row = rb*16 + (ln&15), cols kc*32+(ln>>4)*8 .. +8) as two float4
// (32B contiguous, 32B aligned), converts, writes one v8h per array at base+ln*16B.
__global__ __launch_bounds__(256) void k0_cvt(const float* __restrict__ Q,
                                              const float* __restrict__ K){
  const int bid = blockIdx.x;          // h*128 + rb
  const int t = threadIdx.x;
  const int kc = t >> 6, ln = t & 63;
  const int row = ln & 15;
  const int col = kc*32 + (ln >> 4)*8;
  const size_t src = ((size_t)bid*16 + row)*Dd + col;
  const size_t ob  = (((size_t)bid)*4 + kc)*512 + (size_t)ln*8;

  float4 qa = *(const float4*)(Q + src);
  float4 qb = *(const float4*)(Q + src + 4);
  float qs[8] = {qa.x*SCALE, qa.y*SCALE, qa.z*SCALE, qa.w*SCALE,
                 qb.x*SCALE, qb.y*SCALE, qb.z*SCALE, qb.w*SCALE};
  v8h qh, ql;
  #pragma unroll
  for (int j = 0; j < 8; ++j){
    _Float16 hi = (_Float16)qs[j];
    qh[j] = hi;
    ql[j] = (_Float16)(qs[j] - (float)hi);
  }
  *(v8h*)&g_qh[ob] = qh;
  *(v8h*)&g_ql[ob] = ql;

  float4 ka = *(const float4*)(K + src);
  float4 kb = *(const float4*)(K + src + 4);
  float ks[8] = {ka.x, ka.y, ka.z, ka.w, kb.x, kb.y, kb.z, kb.w};
  v8h kh, kl;
  #pragma unroll
  for (int j = 0; j < 8; ++j){
    _Float16 hi = (_Float16)ks[j];
    kh[j] = hi;
    kl[j] = (_Float16)(ks[j] - (float)hi);
  }
  *(v8h*)&g_kh[ob] = kh;
  *(v8h*)&g_kl[ob] = kl;
}

// ---------------- Kernel 1: MFMA split-fp16 QK -> exp -> row-sum partials ----------------
// 128x128 tile per block, 4 waves x (2 tile-rows x 8 tile-cols) of 16x16x32_f16 MFMAs.
// Fragment loads are base + ln*16B: one contiguous 1KB transaction per instruction.
// D layout (HW-verified m89/m91): col=lane&15, row=quad*4+reg. No LDS, no barriers.
__global__ __launch_bounds__(256) void k1_rowsum(){
  const int bid0 = blockIdx.x;
  const int w = (bid0 & 7)*384 + (bid0 >> 3);   // 3072 blocks, xcd-contiguous
  const int jb = w & 15, gp = (w >> 4) & 15, h = w >> 8;
  const int t = threadIdx.x;
  const int wv = t >> 6, ln = t & 63;
  const int nidx = ln & 15, quad = ln >> 4;
  const size_t lnoff = (size_t)ln*8;
  const size_t habase = ((size_t)h*128 + gp*8 + wv*2)*4;  // +tr*4 +kc, then *512
  const size_t hbbase = ((size_t)h*128 + jb*8)*4;         // +tc*4 +kc, then *512

  v4f acc[2][8];
  #pragma unroll
  for (int tr = 0; tr < 2; ++tr)
    #pragma unroll
    for (int tc = 0; tc < 8; ++tc)
      acc[tr][tc] = (v4f){0.f, 0.f, 0.f, 0.f};

  for (int kc = 0; kc < 4; ++kc){
    v8h ahi[2], alo[2];
    #pragma unroll
    for (int tr = 0; tr < 2; ++tr){
      const size_t ab = (habase + tr*4 + kc)*512 + lnoff;
      ahi[tr] = *(const v8h*)&g_qh[ab];
      alo[tr] = *(const v8h*)&g_ql[ab];
    }
    v8h bhi[8], blo[8];
    #pragma unroll
    for (int tc = 0; tc < 8; ++tc){
      const size_t bb = (hbbase + tc*4 + kc)*512 + lnoff;
      bhi[tc] = *(const v8h*)&g_kh[bb];
      blo[tc] = *(const v8h*)&g_kl[bb];
    }
    #pragma unroll
    for (int tr = 0; tr < 2; ++tr)
      #pragma unroll
      for (int tc = 0; tc < 8; ++tc){
        acc[tr][tc] = __builtin_amdgcn_mfma_f32_16x16x32_f16(ahi[tr], bhi[tc], acc[tr][tc], 0, 0, 0);
        acc[tr][tc] = __builtin_amdgcn_mfma_f32_16x16x32_f16(ahi[tr], blo[tc], acc[tr][tc], 0, 0, 0);
        acc[tr][tc] = __builtin_amdgcn_mfma_f32_16x16x32_f16(alo[tr], bhi[tc], acc[tr][tc], 0, 0, 0);
      }
  }

  // epilogue: exp, shfl-reduced row sums -> g_lp (R1 order: bit-exact l)
  #pragma unroll
  for (int tr = 0; tr < 2; ++tr){
    float rs[4] = {0.f, 0.f, 0.f, 0.f};
    #pragma unroll
    for (int tc = 0; tc < 8; ++tc){
      #pragma unroll
      for (int r = 0; r < 4; ++r){
        rs[r] += __expf(acc[tr][tc][r]);
      }
    }
    #pragma unroll
    for (int r = 0; r < 4; ++r){
      float v = rs[r];
      v += __shfl_xor(v, 1);
      v += __shfl_xor(v, 2);
      v += __shfl_xor(v, 4);
      v += __shfl_xor(v, 8);
      rs[r] = v;
    }
    if (nidx == 0){
      #pragma unroll
      for (int r = 0; r < 4; ++r){
        const int row = (wv*2+tr)*16 + quad*4 + r;
        g_lp[((size_t)h*Nn + gp*128 + row)*16 + jb] = rs[r];
      }
    }
  }
}

// ---------------- Kernel 2r: MFMA QK recompute -> weighted colsum -> g_bs ----------------
// Same tile body as k1. Tile (h,gp,jb) owns bs[g=2gp..2gp+1][cols jb*128..+127].
// il from g_lp x=0..15 ascending (bit-exact). Colsum: r-sum -> xor16/xor32 -> wave pair.
__global__ __launch_bounds__(256) void k2r_colsum(){
  const int bid0 = blockIdx.x;
  const int w = (bid0 & 7)*384 + (bid0 >> 3);   // 3072 blocks, xcd-contiguous
  const int jb = w & 15, gp = (w >> 4) & 15, h = w >> 8;
  const int t = threadIdx.x;
  const int wv = t >> 6, ln = t & 63;
  const int nidx = ln & 15, quad = ln >> 4;
  const size_t lnoff = (size_t)ln*8;
  const size_t habase = ((size_t)h*128 + gp*8 + wv*2)*4;
  const size_t hbbase = ((size_t)h*128 + jb*8)*4;

  __shared__ float il_s[128];
  __shared__ float part[4][128];
  if (t < 128){
    const float* lp = &g_lp[((size_t)h*Nn + gp*128 + t)*16];
    float s = 0.f;
    #pragma unroll
    for (int x = 0; x < 16; ++x) s += lp[x];
    il_s[t] = 1.0f / s;
  }
  __syncthreads();

  v4f acc[2][8];
  #pragma unroll
  for (int tr = 0; tr < 2; ++tr)
    #pragma unroll
    for (int tc = 0; tc < 8; ++tc)
      acc[tr][tc] = (v4f){0.f, 0.f, 0.f, 0.f};

  for (int kc = 0; kc < 4; ++kc){
    v8h ahi[2], alo[2];
    #pragma unroll
    for (int tr = 0; tr < 2; ++tr){
      const size_t ab = (habase + tr*4 + kc)*512 + lnoff;
      ahi[tr] = *(const v8h*)&g_qh[ab];
      alo[tr] = *(const v8h*)&g_ql[ab];
    }
    v8h bhi[8], blo[8];
    #pragma unroll
    for (int tc = 0; tc < 8; ++tc){
      const size_t bb = (hbbase + tc*4 + kc)*512 + lnoff;
      bhi[tc] = *(const v8h*)&g_kh[bb];
      blo[tc] = *(const v8h*)&g_kl[bb];
    }
    #pragma unroll
    for (int tr = 0; tr < 2; ++tr)
      #pragma unroll
      for (int tc = 0; tc < 8; ++tc){
        acc[tr][tc] = __builtin_amdgcn_mfma_f32_16x16x32_f16(ahi[tr], bhi[tc], acc[tr][tc], 0, 0, 0);
        acc[tr][tc] = __builtin_amdgcn_mfma_f32_16x16x32_f16(ahi[tr], blo[tc], acc[tr][tc], 0, 0, 0);
        acc[tr][tc] = __builtin_amdgcn_mfma_f32_16x16x32_f16(alo[tr], bhi[tc], acc[tr][tc], 0, 0, 0);
      }
  }

  // weighted colsum epilogue. Wave wv covers tile rows [wv*32, wv*32+32).
  float csg[8];
  #pragma unroll
  for (int tc = 0; tc < 8; ++tc) csg[tc] = 0.f;
  #pragma unroll
  for (int tr = 0; tr < 2; ++tr){
    #pragma unroll
    for (int tc = 0; tc < 8; ++tc){
      float cs = 0.f;
      #pragma unroll
      for (int r = 0; r < 4; ++r){
        const int row = (wv*2+tr)*16 + quad*4 + r;
        cs += __expf(acc[tr][tc][r]) * il_s[row];
      }
      cs += __shfl_xor(cs, 16);   // sum across the 4 quads (16 rows of this tile-row)
      cs += __shfl_xor(cs, 32);
      csg[tc] += cs;
    }
  }
  if (ln < 16){                    // quad 0 publishes this wave's 128 col-partials
    #pragma unroll
    for (int tc = 0; tc < 8; ++tc) part[wv][tc*16 + nidx] = csg[tc];
  }
  __syncthreads();
  // waves 0+1 = rows 0..63 = group 2gp; waves 2+3 = group 2gp+1
  const int col = t & 127, grp = t >> 7;
  g_bs[((size_t)h*QGg + gp*2 + grp)*Nn + jb*128 + col] =
      part[grp*2][col] + part[grp*2 + 1][col];
}

// ---------------- Kernel 2b: top-k + random + static window -> compacted key list ----------------
__global__ __launch_bounds__(256) void k2b_mask(){
  const int bid = blockIdx.x, g = bid % QGg, t = threadIdx.x;
  __shared__ float bsv[Nn];
  __shared__ int red[33];
  __shared__ int csel;
  const float* src = g_bs + (size_t)bid*Nn;
  float mine[8];
  {
    float4 a = *(const float4*)&src[t*4];
    float4 b = *(const float4*)&src[1024 + t*4];
    *(float4*)&bsv[t*4] = a;
    *(float4*)&bsv[1024 + t*4] = b;
    mine[0]=a.x; mine[1]=a.y; mine[2]=a.z; mine[3]=a.w;
    mine[4]=b.x; mine[5]=b.y; mine[6]=b.z; mine[7]=b.w;
  }
  if (t < 33) red[t] = 0;
  if (t == 0) csel = 0;
  __syncthreads();

  unsigned int k1a, k1b, k2a, k2b;
  tf2x32(0u, 1u, 0u, 0u, k1a, k1b);
  tf2x32(0u, 1u, 0u, 1u, k2a, k2b);

  // 192nd-largest via bitwise binary search (positive -> uint order)
  unsigned int prefix = 0u;
  for (int bit = 31; bit >= 0; --bit){
    unsigned int cand = prefix | (1u << bit);
    int c = 0;
    #pragma unroll
    for (int u = 0; u < 8; ++u)
      c += (__float_as_uint(mine[u]) >= cand) ? 1 : 0;
    #pragma unroll
    for (int off = 32; off > 0; off >>= 1) c += __shfl_down(c, off);
    if ((t & 63) == 0) atomicAdd(&red[bit], c);
    __syncthreads();
    if (red[bit] >= KSEL) prefix = cand;
  }
  {
    int cg = 0;
    #pragma unroll
    for (int u = 0; u < 8; ++u)
      cg += (__float_as_uint(mine[u]) > prefix) ? 1 : 0;
    #pragma unroll
    for (int off = 32; off > 0; off >>= 1) cg += __shfl_down(cg, off);
    if ((t & 63) == 0) atomicAdd(&red[32], cg);
  }
  __syncthreads();
  const int need = KSEL - red[32];   // ties taken lowest-index-first (jax top_k)

  const int lo = g*BMq + BMq/2 - 153;   // ws=int(0.15*2048)=307, ws//2=153
  const int hi = g*BMq + BMq/2 + 153;
  const int ssum = ((hi < Nn) ? hi : Nn) - ((lo > 0) ? lo : 0);
  const bool vqg = (ssum + KSEL) < Nn;  // always true at this config

  #pragma unroll
  for (int u = 0; u < 8; ++u){
    int j = (u < 4) ? (t*4 + u) : (1024 + t*4 + u - 4);
    unsigned int bu = __float_as_uint(mine[u]);
    bool topk = bu > prefix;
    if (!topk && bu == prefix){
      int tr = 0;
      for (int jj = 0; jj < j; ++jj)
        tr += (__float_as_uint(bsv[jj]) == prefix) ? 1 : 0;
      topk = (tr < need);
    }
    bool rnd = jax_rand01((unsigned)(bid*Nn + j), k1a, k1b, k2a, k2b);
    bool st  = (j >= lo) && (j < hi);
    bool selb = st || ((rnd || topk) && vqg);
    if (selb){
      int slot = atomicAdd(&csel, 1);
      g_sel[(size_t)bid*Nn + slot] = (unsigned short)j;
    }
  }
  __syncthreads();
  if (t == 0) g_cnt[bid] = csel;
}

// ---------------- Kernel 3: one-pass attention, XCD-swizzled, NO prefetch ----------------
__global__ __launch_bounds__(256) void k3_attn(const float* __restrict__ Q,
                                               const float* __restrict__ K,
                                               const float* __restrict__ V,
                                               const float* __restrict__ OC,
                                               float* __restrict__ out){
  const int bid0 = blockIdx.x;
  const int w    = (bid0 & 7)*96 + (bid0 >> 3);   // xcd-grouped work index
  const int half = w & 1;
  const int gg   = w >> 1;             // h*QGg + g
  const int h = gg / QGg, g = gg % QGg;
  const int t = threadIdx.x;
  __shared__ float q_s[32][Dd+4];
  __shared__ float kv_s[CK][Dd+4];
  __shared__ float s_s[32][CK+1];
  __shared__ float l_s[32];
  const int c = g_cnt[gg];
  const unsigned short* sel = g_sel + (size_t)gg*Nn;

  const float* qb = Q + ((size_t)h*Nn + (size_t)g*BMq + half*32)*Dd;
  #pragma unroll
  for (int it = 0; it < 4; ++it){
    int e = it*256 + t;                 // 1024 float4s = 32 rows x 32 f4
    int row = e >> 5, c4 = e & 31;
    float4 vq = ((const float4*)qb)[e];
    float4 sv; sv.x = vq.x*SCALE; sv.y = vq.y*SCALE; sv.z = vq.z*SCALE; sv.w = vq.w*SCALE;
    *(float4*)&q_s[row][c4*4] = sv;
  }
  if (t < 32) l_s[t] = 0.0f;
  __syncthreads();

  const int rt = t & 15, kcol = (t >> 4)*2;
  const int d0 = (t >> 4)*8;           // PV column group
  float acc2[2][8] = {};

  for (int c0 = 0; c0 < c; c0 += CK){
    const int cc = ((c - c0) < CK) ? (c - c0) : CK;
    // gather K chunk
    #pragma unroll
    for (int it = 0; it < 4; ++it){
      int e = it*256 + t, row = e >> 5, c4 = e & 31;
      int j = (row < cc) ? (int)sel[c0 + row] : 0;
      *(float4*)&kv_s[row][c4*4] = ((const float4*)(K + ((size_t)h*Nn + j)*Dd))[c4];
    }
    __syncthreads();
    float a00=0.f, a01=0.f, a10=0.f, a11=0.f;
    #pragma unroll 8
    for (int d = 0; d < Dd; d += 4){
      float4 k0 = *(const float4*)&kv_s[kcol][d];
      float4 k1 = *(const float4*)&kv_s[kcol+1][d];
      float4 q0 = *(const float4*)&q_s[rt][d];
      float4 q1 = *(const float4*)&q_s[rt+16][d];
      a00 += q0.x*k0.x + q0.y*k0.y + q0.z*k0.z + q0.w*k0.w;
      a01 += q0.x*k1.x + q0.y*k1.y + q0.z*k1.z + q0.w*k1.w;
      a10 += q1.x*k0.x + q1.y*k0.y + q1.z*k0.z + q1.w*k0.w;
      a11 += q1.x*k1.x + q1.y*k1.y + q1.z*k1.z + q1.w*k1.w;
    }
    s_s[rt   ][kcol  ] = (kcol   < cc) ? __expf(a00) : 0.f;
    s_s[rt   ][kcol+1] = (kcol+1 < cc) ? __expf(a01) : 0.f;
    s_s[rt+16][kcol  ] = (kcol   < cc) ? __expf(a10) : 0.f;
    s_s[rt+16][kcol+1] = (kcol+1 < cc) ? __expf(a11) : 0.f;
    __syncthreads();
    if (t < 32){
      float s = 0.f;
      #pragma unroll
      for (int c2 = 0; c2 < CK; ++c2) s += s_s[t][c2];
      l_s[t] += s;
    }
    // gather V chunk (overwrites kv_s; QK readers already past barrier)
    #pragma unroll
    for (int it = 0; it < 4; ++it){
      int e = it*256 + t, row = e >> 5, c4 = e & 31;
      int j = (row < cc) ? (int)sel[c0 + row] : 0;
      *(float4*)&kv_s[row][c4*4] = ((const float4*)(V + ((size_t)h*Nn + j)*Dd))[c4];
    }
    __syncthreads();
    for (int c2 = 0; c2 < cc; ++c2){
      float p0 = s_s[rt][c2], p1 = s_s[rt+16][c2];
      float4 va = *(const float4*)&kv_s[c2][d0];
      float4 vb = *(const float4*)&kv_s[c2][d0+4];
      acc2[0][0] += p0*va.x; acc2[0][1] += p0*va.y;
      acc2[0][2] += p0*va.z; acc2[0][3] += p0*va.w;
      acc2[0][4] += p0*vb.x; acc2[0][5] += p0*vb.y;
      acc2[0][6] += p0*vb.z; acc2[0][7] += p0*vb.w;
      acc2[1][0] += p1*va.x; acc2[1][1] += p1*va.y;
      acc2[1][2] += p1*va.z; acc2[1][3] += p1*va.w;
      acc2[1][4] += p1*vb.x; acc2[1][5] += p1*vb.y;
      acc2[1][6] += p1*vb.z; acc2[1][7] += p1*vb.w;
    }
    __syncthreads();
  }

  if (t < 32) l_s[t] = 1.0f / l_s[t];
  __syncthreads();

  #pragma unroll
  for (int rr = 0; rr < 2; ++rr){
    const int r = rr*16 + rt;
    const float il = l_s[r];
    size_t o = ((size_t)h*Nn + (size_t)g*BMq + half*32 + r)*Dd + d0;
    float4 ca = *(const float4*)(OC + o);
    float4 cb = *(const float4*)(OC + o + 4);
    float4 ra, rb;
    ra.x = acc2[rr][0]*il + ca.x; ra.y = acc2[rr][1]*il + ca.y;
    ra.z = acc2[rr][2]*il + ca.z; ra.w = acc2[rr][3]*il + ca.w;
    rb.x = acc2[rr][4]*il + cb.x; rb.y = acc2[rr][5]*il + cb.y;
    rb.z = acc2[rr][6]*il + cb.z; rb.w = acc2[rr][7]*il + cb.w;
    *(float4*)(out + o)     = ra;
    *(float4*)(out + o + 4) = rb;
  }
}

extern "C" void kernel_launch(void* const* d_in, const int* in_sizes, int n_in,
                              void* d_out, int out_size, void* d_ws, size_t ws_size,
                              hipStream_t stream) {
  (void)in_sizes; (void)n_in; (void)out_size; (void)d_ws; (void)ws_size;
  const float* Q  = (const float*)d_in[0];
  const float* K  = (const float*)d_in[1];
  const float* V  = (const float*)d_in[2];
  const float* OC = (const float*)d_in[3];
  float* out = (float*)d_out;
  hipLaunchKernelGGL(k0_cvt,     dim3(Hh*128),   dim3(256), 0, stream, Q, K);
  hipLaunchKernelGGL(k1_rowsum,  dim3(Hh*16*16), dim3(256), 0, stream);
  hipLaunchKernelGGL(k2r_colsum, dim3(Hh*16*16), dim3(256), 0, stream);
  hipLaunchKernelGGL(k2b_mask,   dim3(Hh*QGg),   dim3(256), 0, stream);
  hipLaunchKernelGGL(k3_attn,    dim3(Hh*QGg*2), dim3(256), 0, stream, Q, K, V, OC, out);
}

// Round 7
// 347.665 us; speedup vs baseline: 1.7036x; 1.1872x over previous
//
#include <hip/hip_runtime.h>
#include <math.h>

// SparseDiffAttn: B=1,H=12,N=2048,D=128, BM=64, top-k=192, static window [c-153,c+153),
// random keys via modern-JAX randint under jax_threefry_partitionable=True:
//   k1 = tf((0,1),(0,0)), k2 = tf((0,1),(0,1))        [fold-like split]
//   bits(k,i) = b1^b2 with (b1,b2) = tf(k,(0,i))      [partitionable random_bits]
//   offset = ((hi%100)*96 + lo%100) % 100; rnd <=> offset==0
// PRECISION: selection robust to ~1e-6 rel (fp32==fp64 masks) but NOT fp16-E (R10, 5e-4).
// Split-fp16 MFMA QK (hi·hi + hi·lo + lo·hi) err ~1e-7 rel — inside the certified band.
// RULES: (a) no cross-chunk prefetch in k3 (R8/R13); (c) k3 XCD swizzle FETCH 157->28MB.
// R19-R21: QK pass ~180us invariant to everything EXCEPT access pattern.
// R23 CONFIRMED (412.7us): fragment-ordered g_qh/ql/kh/kl ([h][rb16][kc][ln][8], load =
// base+ln*16B = one contiguous 1KB wave transaction) cut k1/k2r from ~168 to ~90us each.
// VMEM line-scatter WAS the wall.
// R24 (this round): k3 was 173us at MfmaUtil=0 / VALUBusy=47% — scalar QK+PV on the
// vector pipe (~128 b128 + 1024 FMA per chunk-thread). Moved both to split-fp16 MFMA:
// A-frags for QK come straight from g_qh/g_ql (hoisted, q_s staging deleted); K gathered
// fp32->LDS then split-converted per kc; V gathered TRANSPOSED into vT[128][33] so the
// PV B-fragment reads are layout-native; P re-read from s_s and split-converted.
// CK=32 = one K=32 MFMA step. Masking, l-order, 4-barrier lockstep, swizzle preserved.
// Selection path (k0/k1/k2r/k2b) byte-identical to R23.
constexpr int Hh   = 12;
constexpr int Nn   = 2048;
constexpr int Dd   = 128;
constexpr int BMq  = 64;
constexpr int QGg  = 32;            // Nn/BMq
constexpr int KSEL = 192;           // 64 * round(0.1*2048/64)
constexpr int CK   = 32;            // key chunk (k3)
constexpr float SCALE = 0.08838834764831845f;  // 1/sqrt(128)

typedef _Float16 v8h __attribute__((ext_vector_type(8)));   // MFMA A/B frag (4 VGPRs)
typedef float    v4f __attribute__((ext_vector_type(4)));   // MFMA C/D frag

// persistent scratch (fully rewritten every launch before any read)
// fragment-ordered: offset(h,rb,kc,ln,e) = (((h*128+rb)*4+kc)*64+ln)*8+e holds original
// element (row = rb*16 + (ln&15), col = kc*32 + (ln>>4)*8 + e).
__device__ __attribute__((aligned(16))) _Float16 g_qh[(size_t)Hh*Nn*Dd];  // Q*SCALE hi
__device__ __attribute__((aligned(16))) _Float16 g_ql[(size_t)Hh*Nn*Dd];  // Q*SCALE lo
__device__ __attribute__((aligned(16))) _Float16 g_kh[(size_t)Hh*Nn*Dd];  // K hi
__device__ __attribute__((aligned(16))) _Float16 g_kl[(size_t)Hh*Nn*Dd];  // K lo
__device__ float          g_lp[(size_t)Hh*Nn*16];           // per-jb partial row sums
__device__ float          g_bs[(size_t)Hh*QGg*Nn];          // colsum scores (3 MB)
__device__ unsigned short g_sel[Hh*QGg*Nn];
__device__ int            g_cnt[Hh*QGg];

__device__ __forceinline__ unsigned int rotl32(unsigned int x, int n){
  return (x << n) | (x >> (32 - n));
}

// threefry2x32, 20 rounds, arbitrary key
__device__ __forceinline__ void tf2x32(unsigned int k0, unsigned int k1,
                                       unsigned int x0, unsigned int x1,
                                       unsigned int &o0, unsigned int &o1){
  const unsigned int ks2 = 0x1BD11BDAu ^ k0 ^ k1;
  x0 += k0; x1 += k1;
  x0 += x1; x1 = rotl32(x1,13); x1 ^= x0;
  x0 += x1; x1 = rotl32(x1,15); x1 ^= x0;
  x0 += x1; x1 = rotl32(x1,26); x1 ^= x0;
  x0 += x1; x1 = rotl32(x1, 6); x1 ^= x0;
  x0 += k1; x1 += ks2 + 1u;
  x0 += x1; x1 = rotl32(x1,17); x1 ^= x0;
  x0 += x1; x1 = rotl32(x1,29); x1 ^= x0;
  x0 += x1; x1 = rotl32(x1,16); x1 ^= x0;
  x0 += x1; x1 = rotl32(x1,24); x1 ^= x0;
  x0 += ks2; x1 += k0 + 2u;
  x0 += x1; x1 = rotl32(x1,13); x1 ^= x0;
  x0 += x1; x1 = rotl32(x1,15); x1 ^= x0;
  x0 += x1; x1 = rotl32(x1,26); x1 ^= x0;
  x0 += x1; x1 = rotl32(x1, 6); x1 ^= x0;
  x0 += k0; x1 += k1 + 3u;
  x0 += x1; x1 = rotl32(x1,17); x1 ^= x0;
  x0 += x1; x1 = rotl32(x1,29); x1 ^= x0;
  x0 += x1; x1 = rotl32(x1,16); x1 ^= x0;
  x0 += x1; x1 = rotl32(x1,24); x1 ^= x0;
  x0 += k1; x1 += ks2 + 4u;
  x0 += x1; x1 = rotl32(x1,13); x1 ^= x0;
  x0 += x1; x1 = rotl32(x1,15); x1 ^= x0;
  x0 += x1; x1 = rotl32(x1,26); x1 ^= x0;
  x0 += x1; x1 = rotl32(x1, 6); x1 ^= x0;
  x0 += ks2; x1 += k0 + 5u;
  o0 = x0; o1 = x1;
}

// partitionable-threefry randint(key(1), ..., 0, 100) == 0 for flat element idx
__device__ __forceinline__ bool jax_rand01(unsigned int idx,
                                           unsigned int k1a, unsigned int k1b,
                                           unsigned int k2a, unsigned int k2b){
  unsigned int h0, h1, l0, l1;
  tf2x32(k1a, k1b, 0u, idx, h0, h1);
  tf2x32(k2a, k2b, 0u, idx, l0, l1);
  unsigned int h = h0 ^ h1;
  unsigned int l = l0 ^ l1;
  unsigned int off = ((h % 100u) * 96u + (l % 100u)) % 100u;
  return off == 0u;
}

// ---------------- Kernel 0: split-fp16 convert + fragment-order relayout (NO LDS) ----------------
__global__ __launch_bounds__(256) void k0_cvt(const float* __restrict__ Q,
                                              const float* __restrict__ K){
  const int bid = blockIdx.x;          // h*128 + rb
  const int t = threadIdx.x;
  const int kc = t >> 6, ln = t & 63;
  const int row = ln & 15;
  const int col = kc*32 + (ln >> 4)*8;
  const size_t src = ((size_t)bid*16 + row)*Dd + col;
  const size_t ob  = (((size_t)bid)*4 + kc)*512 + (size_t)ln*8;

  float4 qa = *(const float4*)(Q + src);
  float4 qb = *(const float4*)(Q + src + 4);
  float qs[8] = {qa.x*SCALE, qa.y*SCALE, qa.z*SCALE, qa.w*SCALE,
                 qb.x*SCALE, qb.y*SCALE, qb.z*SCALE, qb.w*SCALE};
  v8h qh, ql;
  #pragma unroll
  for (int j = 0; j < 8; ++j){
    _Float16 hi = (_Float16)qs[j];
    qh[j] = hi;
    ql[j] = (_Float16)(qs[j] - (float)hi);
  }
  *(v8h*)&g_qh[ob] = qh;
  *(v8h*)&g_ql[ob] = ql;

  float4 ka = *(const float4*)(K + src);
  float4 kb = *(const float4*)(K + src + 4);
  float ks[8] = {ka.x, ka.y, ka.z, ka.w, kb.x, kb.y, kb.z, kb.w};
  v8h kh, kl;
  #pragma unroll
  for (int j = 0; j < 8; ++j){
    _Float16 hi = (_Float16)ks[j];
    kh[j] = hi;
    kl[j] = (_Float16)(ks[j] - (float)hi);
  }
  *(v8h*)&g_kh[ob] = kh;
  *(v8h*)&g_kl[ob] = kl;
}

// ---------------- Kernel 1: MFMA split-fp16 QK -> exp -> row-sum partials ----------------
__global__ __launch_bounds__(256) void k1_rowsum(){
  const int bid0 = blockIdx.x;
  const int w = (bid0 & 7)*384 + (bid0 >> 3);   // 3072 blocks, xcd-contiguous
  const int jb = w & 15, gp = (w >> 4) & 15, h = w >> 8;
  const int t = threadIdx.x;
  const int wv = t >> 6, ln = t & 63;
  const int nidx = ln & 15, quad = ln >> 4;
  const size_t lnoff = (size_t)ln*8;
  const size_t habase = ((size_t)h*128 + gp*8 + wv*2)*4;  // +tr*4 +kc, then *512
  const size_t hbbase = ((size_t)h*128 + jb*8)*4;         // +tc*4 +kc, then *512

  v4f acc[2][8];
  #pragma unroll
  for (int tr = 0; tr < 2; ++tr)
    #pragma unroll
    for (int tc = 0; tc < 8; ++tc)
      acc[tr][tc] = (v4f){0.f, 0.f, 0.f, 0.f};

  for (int kc = 0; kc < 4; ++kc){
    v8h ahi[2], alo[2];
    #pragma unroll
    for (int tr = 0; tr < 2; ++tr){
      const size_t ab = (habase + tr*4 + kc)*512 + lnoff;
      ahi[tr] = *(const v8h*)&g_qh[ab];
      alo[tr] = *(const v8h*)&g_ql[ab];
    }
    v8h bhi[8], blo[8];
    #pragma unroll
    for (int tc = 0; tc < 8; ++tc){
      const size_t bb = (hbbase + tc*4 + kc)*512 + lnoff;
      bhi[tc] = *(const v8h*)&g_kh[bb];
      blo[tc] = *(const v8h*)&g_kl[bb];
    }
    #pragma unroll
    for (int tr = 0; tr < 2; ++tr)
      #pragma unroll
      for (int tc = 0; tc < 8; ++tc){
        acc[tr][tc] = __builtin_amdgcn_mfma_f32_16x16x32_f16(ahi[tr], bhi[tc], acc[tr][tc], 0, 0, 0);
        acc[tr][tc] = __builtin_amdgcn_mfma_f32_16x16x32_f16(ahi[tr], blo[tc], acc[tr][tc], 0, 0, 0);
        acc[tr][tc] = __builtin_amdgcn_mfma_f32_16x16x32_f16(alo[tr], bhi[tc], acc[tr][tc], 0, 0, 0);
      }
  }

  // epilogue: exp, shfl-reduced row sums -> g_lp (R1 order: bit-exact l)
  #pragma unroll
  for (int tr = 0; tr < 2; ++tr){
    float rs[4] = {0.f, 0.f, 0.f, 0.f};
    #pragma unroll
    for (int tc = 0; tc < 8; ++tc){
      #pragma unroll
      for (int r = 0; r < 4; ++r){
        rs[r] += __expf(acc[tr][tc][r]);
      }
    }
    #pragma unroll
    for (int r = 0; r < 4; ++r){
      float v = rs[r];
      v += __shfl_xor(v, 1);
      v += __shfl_xor(v, 2);
      v += __shfl_xor(v, 4);
      v += __shfl_xor(v, 8);
      rs[r] = v;
    }
    if (nidx == 0){
      #pragma unroll
      for (int r = 0; r < 4; ++r){
        const int row = (wv*2+tr)*16 + quad*4 + r;
        g_lp[((size_t)h*Nn + gp*128 + row)*16 + jb] = rs[r];
      }
    }
  }
}

// ---------------- Kernel 2r: MFMA QK recompute -> weighted colsum -> g_bs ----------------
__global__ __launch_bounds__(256) void k2r_colsum(){
  const int bid0 = blockIdx.x;
  const int w = (bid0 & 7)*384 + (bid0 >> 3);   // 3072 blocks, xcd-contiguous
  const int jb = w & 15, gp = (w >> 4) & 15, h = w >> 8;
  const int t = threadIdx.x;
  const int wv = t >> 6, ln = t & 63;
  const int nidx = ln & 15, quad = ln >> 4;
  const size_t lnoff = (size_t)ln*8;
  const size_t habase = ((size_t)h*128 + gp*8 + wv*2)*4;
  const size_t hbbase = ((size_t)h*128 + jb*8)*4;

  __shared__ float il_s[128];
  __shared__ float part[4][128];
  if (t < 128){
    const float* lp = &g_lp[((size_t)h*Nn + gp*128 + t)*16];
    float s = 0.f;
    #pragma unroll
    for (int x = 0; x < 16; ++x) s += lp[x];
    il_s[t] = 1.0f / s;
  }
  __syncthreads();

  v4f acc[2][8];
  #pragma unroll
  for (int tr = 0; tr < 2; ++tr)
    #pragma unroll
    for (int tc = 0; tc < 8; ++tc)
      acc[tr][tc] = (v4f){0.f, 0.f, 0.f, 0.f};

  for (int kc = 0; kc < 4; ++kc){
    v8h ahi[2], alo[2];
    #pragma unroll
    for (int tr = 0; tr < 2; ++tr){
      const size_t ab = (habase + tr*4 + kc)*512 + lnoff;
      ahi[tr] = *(const v8h*)&g_qh[ab];
      alo[tr] = *(const v8h*)&g_ql[ab];
    }
    v8h bhi[8], blo[8];
    #pragma unroll
    for (int tc = 0; tc < 8; ++tc){
      const size_t bb = (hbbase + tc*4 + kc)*512 + lnoff;
      bhi[tc] = *(const v8h*)&g_kh[bb];
      blo[tc] = *(const v8h*)&g_kl[bb];
    }
    #pragma unroll
    for (int tr = 0; tr < 2; ++tr)
      #pragma unroll
      for (int tc = 0; tc < 8; ++tc){
        acc[tr][tc] = __builtin_amdgcn_mfma_f32_16x16x32_f16(ahi[tr], bhi[tc], acc[tr][tc], 0, 0, 0);
        acc[tr][tc] = __builtin_amdgcn_mfma_f32_16x16x32_f16(ahi[tr], blo[tc], acc[tr][tc], 0, 0, 0);
        acc[tr][tc] = __builtin_amdgcn_mfma_f32_16x16x32_f16(alo[tr], bhi[tc], acc[tr][tc], 0, 0, 0);
      }
  }

  // weighted colsum epilogue. Wave wv covers tile rows [wv*32, wv*32+32).
  float csg[8];
  #pragma unroll
  for (int tc = 0; tc < 8; ++tc) csg[tc] = 0.f;
  #pragma unroll
  for (int tr = 0; tr < 2; ++tr){
    #pragma unroll
    for (int tc = 0; tc < 8; ++tc){
      float cs = 0.f;
      #pragma unroll
      for (int r = 0; r < 4; ++r){
        const int row = (wv*2+tr)*16 + quad*4 + r;
        cs += __expf(acc[tr][tc][r]) * il_s[row];
      }
      cs += __shfl_xor(cs, 16);   // sum across the 4 quads (16 rows of this tile-row)
      cs += __shfl_xor(cs, 32);
      csg[tc] += cs;
    }
  }
  if (ln < 16){                    // quad 0 publishes this wave's 128 col-partials
    #pragma unroll
    for (int tc = 0; tc < 8; ++tc) part[wv][tc*16 + nidx] = csg[tc];
  }
  __syncthreads();
  // waves 0+1 = rows 0..63 = group 2gp; waves 2+3 = group 2gp+1
  const int col = t & 127, grp = t >> 7;
  g_bs[((size_t)h*QGg + gp*2 + grp)*Nn + jb*128 + col] =
      part[grp*2][col] + part[grp*2 + 1][col];
}

// ---------------- Kernel 2b: top-k + random + static window -> compacted key list ----------------
__global__ __launch_bounds__(256) void k2b_mask(){
  const int bid = blockIdx.x, g = bid % QGg, t = threadIdx.x;
  __shared__ float bsv[Nn];
  __shared__ int red[33];
  __shared__ int csel;
  const float* src = g_bs + (size_t)bid*Nn;
  float mine[8];
  {
    float4 a = *(const float4*)&src[t*4];
    float4 b = *(const float4*)&src[1024 + t*4];
    *(float4*)&bsv[t*4] = a;
    *(float4*)&bsv[1024 + t*4] = b;
    mine[0]=a.x; mine[1]=a.y; mine[2]=a.z; mine[3]=a.w;
    mine[4]=b.x; mine[5]=b.y; mine[6]=b.z; mine[7]=b.w;
  }
  if (t < 33) red[t] = 0;
  if (t == 0) csel = 0;
  __syncthreads();

  unsigned int k1a, k1b, k2a, k2b;
  tf2x32(0u, 1u, 0u, 0u, k1a, k1b);
  tf2x32(0u, 1u, 0u, 1u, k2a, k2b);

  // 192nd-largest via bitwise binary search (positive -> uint order)
  unsigned int prefix = 0u;
  for (int bit = 31; bit >= 0; --bit){
    unsigned int cand = prefix | (1u << bit);
    int c = 0;
    #pragma unroll
    for (int u = 0; u < 8; ++u)
      c += (__float_as_uint(mine[u]) >= cand) ? 1 : 0;
    #pragma unroll
    for (int off = 32; off > 0; off >>= 1) c += __shfl_down(c, off);
    if ((t & 63) == 0) atomicAdd(&red[bit], c);
    __syncthreads();
    if (red[bit] >= KSEL) prefix = cand;
  }
  {
    int cg = 0;
    #pragma unroll
    for (int u = 0; u < 8; ++u)
      cg += (__float_as_uint(mine[u]) > prefix) ? 1 : 0;
    #pragma unroll
    for (int off = 32; off > 0; off >>= 1) cg += __shfl_down(cg, off);
    if ((t & 63) == 0) atomicAdd(&red[32], cg);
  }
  __syncthreads();
  const int need = KSEL - red[32];   // ties taken lowest-index-first (jax top_k)

  const int lo = g*BMq + BMq/2 - 153;   // ws=int(0.15*2048)=307, ws//2=153
  const int hi = g*BMq + BMq/2 + 153;
  const int ssum = ((hi < Nn) ? hi : Nn) - ((lo > 0) ? lo : 0);
  const bool vqg = (ssum + KSEL) < Nn;  // always true at this config

  #pragma unroll
  for (int u = 0; u < 8; ++u){
    int j = (u < 4) ? (t*4 + u) : (1024 + t*4 + u - 4);
    unsigned int bu = __float_as_uint(mine[u]);
    bool topk = bu > prefix;
    if (!topk && bu == prefix){
      int tr = 0;
      for (int jj = 0; jj < j; ++jj)
        tr += (__float_as_uint(bsv[jj]) == prefix) ? 1 : 0;
      topk = (tr < need);
    }
    bool rnd = jax_rand01((unsigned)(bid*Nn + j), k1a, k1b, k2a, k2b);
    bool st  = (j >= lo) && (j < hi);
    bool selb = st || ((rnd || topk) && vqg);
    if (selb){
      int slot = atomicAdd(&csel, 1);
      g_sel[(size_t)bid*Nn + slot] = (unsigned short)j;
    }
  }
  __syncthreads();
  if (t == 0) g_cnt[bid] = csel;
}

// ---------------- Kernel 3: one-pass attention, MFMA QK+PV, XCD-swizzled ----------------
// 4 waves: wave wv -> (qtile = wv>>1, kdt = wv&1). QK: score tile (qtile, ktile=kdt).
// PV: out tiles (qtile, dtiles kdt*4..kdt*4+3). A-frags (Q) hoisted from g_qh/g_ql
// (fragment-ordered, pre-scaled). K gathered fp32->LDS, split-converted per kc.
// V gathered transposed into vT[128][33]; P re-read from s_s. All split-fp16 (3 MFMA).
// D layout (HW-verified): col=lane&15, row=quad*4+reg. Same 4-barrier chunk lockstep.
__global__ __launch_bounds__(256) void k3_attn(const float* __restrict__ K,
                                               const float* __restrict__ V,
                                               const float* __restrict__ OC,
                                               float* __restrict__ out){
  const int bid0 = blockIdx.x;
  const int w    = (bid0 & 7)*96 + (bid0 >> 3);   // xcd-grouped work index
  const int half = w & 1;
  const int gg   = w >> 1;             // h*QGg + g
  const int h = gg / QGg, g = gg % QGg;
  const int t = threadIdx.x;
  const int wv = t >> 6, ln = t & 63;
  const int nidx = ln & 15, quad = ln >> 4;
  const int qtile = wv >> 1, kdt = wv & 1;

  __shared__ float kv_s[CK][132];      // K chunk, row-major (row stride 528B, 16B-aligned)
  __shared__ float vT[Dd][33];         // V chunk transposed: vT[d][key]
  __shared__ float s_s[32][33];        // P = exp(scores)
  __shared__ float l_s[32];

  const int c = g_cnt[gg];
  const unsigned short* sel = g_sel + (size_t)gg*Nn;

  // hoisted Q A-fragments (pre-scaled split-fp16, fragment-ordered, L2-hot)
  const int rb = g*4 + half*2 + qtile;
  v8h aHi[4], aLo[4];
  #pragma unroll
  for (int kc = 0; kc < 4; ++kc){
    const size_t ab = (((size_t)h*128 + rb)*4 + kc)*512 + (size_t)ln*8;
    aHi[kc] = *(const v8h*)&g_qh[ab];
    aLo[kc] = *(const v8h*)&g_ql[ab];
  }

  if (t < 32) l_s[t] = 0.0f;
  __syncthreads();

  v4f acc[4];
  #pragma unroll
  for (int dt = 0; dt < 4; ++dt) acc[dt] = (v4f){0.f, 0.f, 0.f, 0.f};

  for (int c0 = 0; c0 < c; c0 += CK){
    const int cc = ((c - c0) < CK) ? (c - c0) : CK;
    // gather K chunk (row-major fp32)
    #pragma unroll
    for (int it = 0; it < 4; ++it){
      int e = it*256 + t, row = e >> 5, c4 = e & 31;
      int j = (row < cc) ? (int)sel[c0 + row] : 0;
      *(float4*)&kv_s[row][c4*4] = ((const float4*)(K + ((size_t)h*Nn + j)*Dd))[c4];
    }
    __syncthreads();
    // QK: wave tile (qtile, kdt); split-fp16 MFMA over 4 kc steps
    v4f sc = (v4f){0.f, 0.f, 0.f, 0.f};
    #pragma unroll
    for (int kc = 0; kc < 4; ++kc){
      const float* kp = &kv_s[kdt*16 + nidx][kc*32 + quad*8];
      float4 kA = *(const float4*)kp;
      float4 kB = *(const float4*)(kp + 4);
      float xs[8] = {kA.x,kA.y,kA.z,kA.w, kB.x,kB.y,kB.z,kB.w};
      v8h bh, bl;
      #pragma unroll
      for (int jj = 0; jj < 8; ++jj){
        _Float16 hi = (_Float16)xs[jj];
        bh[jj] = hi;
        bl[jj] = (_Float16)(xs[jj] - (float)hi);
      }
      sc = __builtin_amdgcn_mfma_f32_16x16x32_f16(aHi[kc], bh, sc, 0, 0, 0);
      sc = __builtin_amdgcn_mfma_f32_16x16x32_f16(aHi[kc], bl, sc, 0, 0, 0);
      sc = __builtin_amdgcn_mfma_f32_16x16x32_f16(aLo[kc], bh, sc, 0, 0, 0);
    }
    {
      const int k_loc = kdt*16 + nidx;
      #pragma unroll
      for (int r = 0; r < 4; ++r){
        float sv = (k_loc < cc) ? __expf(sc[r]) : 0.f;
        s_s[qtile*16 + quad*4 + r][k_loc] = sv;
      }
    }
    __syncthreads();
    if (t < 32){
      float s = 0.f;
      #pragma unroll
      for (int c2 = 0; c2 < CK; ++c2) s += s_s[t][c2];
      l_s[t] += s;
    }
    // gather V chunk transposed into vT (4-way-conflict scalar writes, paid once)
    #pragma unroll
    for (int it = 0; it < 4; ++it){
      int e = it*256 + t, row = e >> 5, c4 = e & 31;
      int j = (row < cc) ? (int)sel[c0 + row] : 0;
      float4 vv = ((const float4*)(V + ((size_t)h*Nn + j)*Dd))[c4];
      vT[c4*4+0][row] = vv.x;
      vT[c4*4+1][row] = vv.y;
      vT[c4*4+2][row] = vv.z;
      vT[c4*4+3][row] = vv.w;
    }
    __syncthreads();
    // PV: P fragment (shared across this wave's 4 dtiles) + V fragments, split-fp16
    {
      v8h ph, pl;
      #pragma unroll
      for (int jj = 0; jj < 8; ++jj){
        float pv = s_s[qtile*16 + nidx][quad*8 + jj];
        _Float16 hi = (_Float16)pv;
        ph[jj] = hi;
        pl[jj] = (_Float16)(pv - (float)hi);
      }
      #pragma unroll
      for (int dt = 0; dt < 4; ++dt){
        const int d = (kdt*4 + dt)*16 + nidx;
        v8h vh, vl;
        #pragma unroll
        for (int jj = 0; jj < 8; ++jj){
          float vv = vT[d][quad*8 + jj];
          _Float16 hi = (_Float16)vv;
          vh[jj] = hi;
          vl[jj] = (_Float16)(vv - (float)hi);
        }
        acc[dt] = __builtin_amdgcn_mfma_f32_16x16x32_f16(ph, vh, acc[dt], 0, 0, 0);
        acc[dt] = __builtin_amdgcn_mfma_f32_16x16x32_f16(ph, vl, acc[dt], 0, 0, 0);
        acc[dt] = __builtin_amdgcn_mfma_f32_16x16x32_f16(pl, vh, acc[dt], 0, 0, 0);
      }
    }
    __syncthreads();
  }

  if (t < 32) l_s[t] = 1.0f / l_s[t];
  __syncthreads();

  #pragma unroll
  for (int dt = 0; dt < 4; ++dt){
    const int d = (kdt*4 + dt)*16 + nidx;
    #pragma unroll
    for (int r = 0; r < 4; ++r){
      const int row = qtile*16 + quad*4 + r;
      const float il = l_s[row];
      const size_t o = ((size_t)h*Nn + (size_t)g*BMq + half*32 + row)*Dd + d;
      out[o] = acc[dt][r]*il + OC[o];
    }
  }
}

extern "C" void kernel_launch(void* const* d_in, const int* in_sizes, int n_in,
                              void* d_out, int out_size, void* d_ws, size_t ws_size,
                              hipStream_t stream) {
  (void)in_sizes; (void)n_in; (void)out_size; (void)d_ws; (void)ws_size;
  const float* Q  = (const float*)d_in[0];
  const float* K  = (const float*)d_in[1];
  const float* V  = (const float*)d_in[2];
  const float* OC = (const float*)d_in[3];
  float* out = (float*)d_out;
  hipLaunchKernelGGL(k0_cvt,     dim3(Hh*128),   dim3(256), 0, stream, Q, K);
  hipLaunchKernelGGL(k1_rowsum,  dim3(Hh*16*16), dim3(256), 0, stream);
  hipLaunchKernelGGL(k2r_colsum, dim3(Hh*16*16), dim3(256), 0, stream);
  hipLaunchKernelGGL(k2b_mask,   dim3(Hh*QGg),   dim3(256), 0, stream);
  hipLaunchKernelGGL(k3_attn,    dim3(Hh*QGg*2), dim3(256), 0, stream, K, V, OC, out);
}